// Round 1
// baseline (413.732 us; speedup 1.0000x reference)
//
#include <hip/hip_runtime.h>
#include <math.h>

#define NXY    192
#define CELLS  (NXY*NXY)
#define NBATCH 4
#define NSTEPS 256
#define TCH    32                 // steps per chunk (= halo width)
#define NCHUNK (NSTEPS/TCH)       // 8
#define SOUT   32                 // out-tile edge
#define SIN    96                 // in-tile edge (SOUT + 2*TCH)
#define NBLK   6                  // out-tiles per dim per batch
#define TPB    256
#define IMGS   97                 // LDS image stride (96 data + 1 zero ring)

// workspace layout (float offsets)
#define K3_OFF (16*CELLS)         // 2 parity * 2 fields * 4 batch arrays first
#define A1_OFF (K3_OFF + CELLS)
#define I_OFF  (A1_OFF + CELLS)

__device__ __forceinline__ float pml_prof(int i) {
    // v[k] = 3*(k/20)^4 ; bx[i]=v[20-i] for i<=20, v[i-171] for i>=171, else 0
    int t;
    if (i <= 20)            t = 20 - i;
    else if (i >= NXY - 21) t = i - (NXY - 21);
    else                    return 0.0f;
    float u  = (float)t * 0.05f;
    float u2 = u * u;
    return 3.0f * u2 * u2;
}

__global__ void setup_k(const float* __restrict__ rho, float* __restrict__ ws) {
    int idx    = blockIdx.x * blockDim.x + threadIdx.x;
    int stride = gridDim.x * blockDim.x;
    // zero parity-0 field arrays (cur+prev, all batches) = first 8*CELLS floats
    for (int k = idx; k < 8 * CELLS; k += stride) ws[k] = 0.0f;
    // coefficients
    const float IH2 = (float)(1.0 / (2.01 * 2.01));
    for (int k = idx; k < CELLS; k += stride) {
        int i = k / NXY, j = k % NXY;
        float r0 = rho[k];
        float ru = (i > 0)       ? rho[k - NXY] : 0.0f;
        float rd = (i < NXY - 1) ? rho[k + NXY] : 0.0f;
        float rl = (j > 0)       ? rho[k - 1]   : 0.0f;
        float rr = (j < NXY - 1) ? rho[k + 1]   : 0.0f;
        float lpf = 0.5f * r0 + 0.125f * ((ru + rd) + (rl + rr));
        float p   = 0.5f * (1.0f + tanhf(100.0f * (lpf - 0.5f)));
        float c   = 1.0f - 0.1f * p;
        float c2h = c * c * IH2;
        float bx = pml_prof(i), by = pml_prof(j);
        float bb = sqrtf(bx * bx + by * by);
        float a1 = 1.0f / (1.0f + 0.5f * bb);
        ws[K3_OFF + k] = a1 * c2h;
        ws[A1_OFF + k] = a1;
    }
    if (idx < 12) ws[I_OFF + idx] = 0.0f;
}

__global__ __launch_bounds__(TPB, 1)
void chunk_k(const float* __restrict__ x, float* __restrict__ ws, int chunk) {
    int blk = blockIdx.x;
    int b   = blk / (NBLK * NBLK);
    int r6  = blk % (NBLK * NBLK);
    int bi  = r6 / NBLK, bj = r6 % NBLK;
    int I0  = SOUT * bi - TCH;          // in-tile origin (may be negative)
    int J0  = SOUT * bj - TCH;
    int t   = threadIdx.x;
    int ti  = t >> 4, tj = t & 15;      // 16x16 thread grid, 6x6 cells each
    int gi0 = I0 + 6 * ti, gj0 = J0 + 6 * tj;

    __shared__ float img[IMGS * IMGS];  // halo image; row/col 96 = permanent zeros
    __shared__ float xs_l[TCH];

    for (int k = t; k < IMGS * IMGS; k += TPB) img[k] = 0.0f;
    if (t < TCH) xs_l[t] = x[b * NSTEPS + chunk * TCH + t];

    const float* k3g = ws + K3_OFF;
    const float* a1g = ws + A1_OFF;
    int pin = chunk & 1, pout = pin ^ 1;
    const float* curg  = ws + ((pin  * 2 + 0) * NBATCH + b) * CELLS;
    const float* prvg  = ws + ((pin  * 2 + 1) * NBATCH + b) * CELLS;
    float*       ncurg = ws + ((pout * 2 + 0) * NBATCH + b) * CELLS;
    float*       nprvg = ws + ((pout * 2 + 1) * NBATCH + b) * CELLS;

    float yc[6][6], yp[6][6], Pa[6][6], Qa[6][6], Ka[6][6];
#pragma unroll
    for (int r = 0; r < 6; r++) {
#pragma unroll
        for (int c = 0; c < 6; c++) {
            int gi = gi0 + r, gj = gj0 + c;
            bool in = (gi >= 0 && gi < NXY && gj >= 0 && gj < NXY);
            float k3 = 0.f, a1 = 0.f, y1 = 0.f, y2 = 0.f;
            if (in) {
                int idx = gi * NXY + gj;
                k3 = k3g[idx]; a1 = a1g[idx];
                y1 = curg[idx]; y2 = prvg[idx];
            }
            yc[r][c] = y1; yp[r][c] = y2;
            if (in) {
                Ka[r][c] = k3;
                Pa[r][c] = 2.0f * a1 - 4.0f * k3;
                Qa[r][c] = 1.0f - 2.0f * a1;
            } else {
                Ka[r][c] = 0.f; Pa[r][c] = 0.f; Qa[r][c] = 0.f;
            }
        }
    }

    // source / probe bookkeeping
    bool has_src = (I0 <= 40 && 40 < I0 + SIN) && (J0 <= 96 && 96 < J0 + SIN);
    float rs[6], cs[6];
#pragma unroll
    for (int r = 0; r < 6; r++) rs[r] = (gi0 + r == 40) ? 1.0f : 0.0f;
#pragma unroll
    for (int c = 0; c < 6; c++) cs[c] = (gj0 + c == 96) ? 1.0f : 0.0f;

    bool has_prb = (bi == NBLK - 1) && (bj == 1 || bj == 3 || bj == 4);
    int pc  = (bj == 1) ? 48 : (bj == 3) ? 96 : 144;
    int pid = (bj == 1) ? 0  : (bj == 3) ? 1  : 2;
    float rp[6], cp[6];
#pragma unroll
    for (int r = 0; r < 6; r++) rp[r] = (gi0 + r == 160) ? 1.0f : 0.0f;
#pragma unroll
    for (int c = 0; c < 6; c++) cp[c] = (gj0 + c == pc) ? 1.0f : 0.0f;
    bool owner = has_prb && (160 - gi0 >= 0 && 160 - gi0 < 6)
                         && (pc  - gj0 >= 0 && pc  - gj0 < 6);
    float pacc = 0.0f;

    // hoisted halo-read bases (zero ring at row/col 96)
    int up_b = ((ti == 0)  ? 96 : 6 * ti - 1) * IMGS + 6 * tj;
    int dn_b = ((ti == 15) ? 96 : 6 * ti + 6) * IMGS + 6 * tj;
    int lf_b = (6 * ti) * IMGS + ((tj == 0)  ? 96 : 6 * tj - 1);
    int rt_b = (6 * ti) * IMGS + ((tj == 15) ? 96 : 6 * tj + 6);

    __syncthreads();   // img zero + xs_l ready

#define STEP(CUR, PRV, SIDX) do {                                              \
    _Pragma("unroll")                                                          \
    for (int c = 0; c < 6; c++) {                                              \
        img[(6*ti    ) * IMGS + 6*tj + c] = CUR[0][c];                         \
        img[(6*ti + 5) * IMGS + 6*tj + c] = CUR[5][c];                         \
    }                                                                          \
    _Pragma("unroll")                                                          \
    for (int r = 1; r < 5; r++) {                                              \
        img[(6*ti + r) * IMGS + 6*tj    ] = CUR[r][0];                         \
        img[(6*ti + r) * IMGS + 6*tj + 5] = CUR[r][5];                         \
    }                                                                          \
    __syncthreads();                                                           \
    float xsv = xs_l[SIDX];                                                    \
    _Pragma("unroll")                                                          \
    for (int r = 0; r < 6; r++) {                                              \
        _Pragma("unroll")                                                      \
        for (int c = 0; c < 6; c++) {                                          \
            float up = (r > 0) ? CUR[r-1][c] : img[up_b + c];                  \
            float dn = (r < 5) ? CUR[r+1][c] : img[dn_b + c];                  \
            float lf = (c > 0) ? CUR[r][c-1] : img[lf_b + r * IMGS];           \
            float rt = (c < 5) ? CUR[r][c+1] : img[rt_b + r * IMGS];           \
            float yn = Pa[r][c] * CUR[r][c] + Qa[r][c] * PRV[r][c]             \
                     + Ka[r][c] * ((up + dn) + (lf + rt));                     \
            if (has_src) yn += (rs[r] * cs[c]) * xsv;                          \
            if (has_prb) { float tt = rp[r] * cp[c] * yn; pacc += tt * yn; }   \
            PRV[r][c] = yn;                                                    \
        }                                                                      \
    }                                                                          \
    __syncthreads();                                                           \
} while (0)

#pragma unroll 1
    for (int s2 = 0; s2 < TCH / 2; s2++) {
        STEP(yc, yp, 2 * s2);       // writes step result into yp (new cur)
        STEP(yp, yc, 2 * s2 + 1);   // back into yc
    }
#undef STEP
    // after 32 steps: yc = y(t_end), yp = y(t_end - 1)

#pragma unroll
    for (int r = 0; r < 6; r++) {
#pragma unroll
        for (int c = 0; c < 6; c++) {
            int gi = gi0 + r, gj = gj0 + c;
            if (gi >= SOUT * bi && gi < SOUT * bi + SOUT &&
                gj >= SOUT * bj && gj < SOUT * bj + SOUT) {
                int idx = gi * NXY + gj;
                ncurg[idx] = yc[r][c];
                nprvg[idx] = yp[r][c];
            }
        }
    }
    if (owner) ws[I_OFF + b * 3 + pid] += pacc;   // unique writer per (b,pid)
}

__global__ void final_k(const float* __restrict__ ws, float* __restrict__ out) {
    int t = threadIdx.x;
    if (t < 12) {
        const float* I = ws + I_OFF;
        int b = t / 3;
        float s = I[3 * b] + I[3 * b + 1] + I[3 * b + 2];
        out[t] = I[t] / s;
    }
}

extern "C" void kernel_launch(void* const* d_in, const int* in_sizes, int n_in,
                              void* d_out, int out_size, void* d_ws, size_t ws_size,
                              hipStream_t stream) {
    const float* x   = (const float*)d_in[0];   // (4,256) fp32
    const float* rho = (const float*)d_in[1];   // (192,192) fp32
    float* ws  = (float*)d_ws;                  // needs ~2.66 MB
    float* out = (float*)d_out;                 // 12 fp32

    setup_k<<<256, 256, 0, stream>>>(rho, ws);
    for (int c = 0; c < NCHUNK; c++)
        chunk_k<<<NBATCH * NBLK * NBLK, TPB, 0, stream>>>(x, ws, c);
    final_k<<<1, 64, 0, stream>>>(ws, out);
}

// Round 2
// 326.809 us; speedup vs baseline: 1.2660x; 1.2660x over previous
//
#include <hip/hip_runtime.h>
#include <math.h>

#define NXY    192
#define CELLS  (NXY*NXY)
#define NBATCH 4
#define NSTEPS 256
#define TCH    32                 // steps per chunk (= halo width)
#define NCHUNK (NSTEPS/TCH)       // 8
#define TPB    512                // 8 waves
#define NW     8                  // waves per block
#define RPL    12                 // rows per lane (96 / 8 waves)
// in-tile 128 wide x 96 tall; out-tile 64 wide x 32 tall
// grid per batch: 6 row-tiles x 3 col-tiles = 18; total 72 blocks

// workspace layout (float offsets) — identical to round 1 (proven to fit)
#define K3_OFF (16*CELLS)
#define A1_OFF (K3_OFF + CELLS)
#define I_OFF  (A1_OFF + CELLS)

__device__ __forceinline__ float pml_prof(int i) {
    int t;
    if (i <= 20)            t = 20 - i;
    else if (i >= NXY - 21) t = i - (NXY - 21);
    else                    return 0.0f;
    float u  = (float)t * 0.05f;
    float u2 = u * u;
    return 3.0f * u2 * u2;
}

__global__ void setup_k(const float* __restrict__ rho, float* __restrict__ ws) {
    int idx    = blockIdx.x * blockDim.x + threadIdx.x;
    int stride = gridDim.x * blockDim.x;
    for (int k = idx; k < 8 * CELLS; k += stride) ws[k] = 0.0f;
    const float IH2 = (float)(1.0 / (2.01 * 2.01));
    for (int k = idx; k < CELLS; k += stride) {
        int i = k / NXY, j = k % NXY;
        float r0 = rho[k];
        float ru = (i > 0)       ? rho[k - NXY] : 0.0f;
        float rd = (i < NXY - 1) ? rho[k + NXY] : 0.0f;
        float rl = (j > 0)       ? rho[k - 1]   : 0.0f;
        float rr = (j < NXY - 1) ? rho[k + 1]   : 0.0f;
        float lpf = 0.5f * r0 + 0.125f * ((ru + rd) + (rl + rr));
        float p   = 0.5f * (1.0f + tanhf(100.0f * (lpf - 0.5f)));
        float c   = 1.0f - 0.1f * p;
        float c2h = c * c * IH2;
        float bx = pml_prof(i), by = pml_prof(j);
        float bb = sqrtf(bx * bx + by * by);
        float a1 = 1.0f / (1.0f + 0.5f * bb);
        ws[K3_OFF + k] = a1 * c2h;     // K
        ws[A1_OFF + k] = a1;           // A1 (P,Q derived at load time)
    }
    if (idx < 12) ws[I_OFF + idx] = 0.0f;
}

__global__ __launch_bounds__(TPB, 2)
void chunk_k(const float* __restrict__ x, float* __restrict__ ws, int chunk) {
    int blk = blockIdx.x;
    int b  = blk / 18;
    int rr = blk % 18;
    int bi = rr / 3, bj = rr % 3;
    int I0 = 32 * bi - 32;            // in-tile row origin (may be <0)
    int J0 = 64 * bj - 32;            // in-tile col origin (may be <0)
    int t  = threadIdx.x;
    int w  = t >> 6;                  // wave 0..7, owns rows [12w, 12w+12)
    int l  = t & 63;                  // lane, owns cols 2l, 2l+1 (local)
    int row0 = I0 + RPL * w;          // global row of local r=0
    int gj   = J0 + 2 * l;            // global col of c0 (even)

    // band-boundary halo buffers: [parity][top/bot][slot 0..9][lane]
    // slot w+1 = wave w; slots 0 and 9 stay zero (outside in-tile)
    __shared__ float2 hb[2][2][10][64];
    __shared__ float xs_l[TCH];

    for (int k = t; k < 2 * 2 * 10 * 64; k += TPB)
        ((float2*)hb)[k] = make_float2(0.f, 0.f);
    if (t < TCH) xs_l[t] = x[b * NSTEPS + chunk * TCH + t];

    const float* kg = ws + K3_OFF;
    const float* ag = ws + A1_OFF;
    int pin = chunk & 1, pout = pin ^ 1;
    const float* curg  = ws + ((pin  * 2 + 0) * NBATCH + b) * CELLS;
    const float* prvg  = ws + ((pin  * 2 + 1) * NBATCH + b) * CELLS;
    float*       ncurg = ws + ((pout * 2 + 0) * NBATCH + b) * CELLS;
    float*       nprvg = ws + ((pout * 2 + 1) * NBATCH + b) * CELLS;

    float yc[RPL][2], yp[RPL][2], Pa[RPL][2], Qa[RPL][2], Ka[RPL][2];
    bool cok = (gj >= 0 && gj < NXY);
#pragma unroll
    for (int r = 0; r < RPL; r++) {
        int gi = row0 + r;
        bool ok = cok && gi >= 0 && gi < NXY;
        float2 kv = {0.f,0.f}, av = {0.f,0.f}, cv = {0.f,0.f}, pv = {0.f,0.f};
        if (ok) {
            int idx = gi * NXY + gj;
            kv = *(const float2*)(kg + idx);
            av = *(const float2*)(ag + idx);
            cv = *(const float2*)(curg + idx);
            pv = *(const float2*)(prvg + idx);
        }
        yc[r][0] = cv.x; yc[r][1] = cv.y;
        yp[r][0] = pv.x; yp[r][1] = pv.y;
        Ka[r][0] = kv.x; Ka[r][1] = kv.y;
        Pa[r][0] = 2.f * av.x - 4.f * kv.x;
        Pa[r][1] = 2.f * av.y - 4.f * kv.y;
        // out-of-domain: av=kv=0 -> P=K=0, Q=1 keeps y=0 forever (harmless),
        // but zero it for clarity:
        Qa[r][0] = ok ? (1.f - 2.f * av.x) : 0.f;
        Qa[r][1] = ok ? (1.f - 2.f * av.y) : 0.f;
    }

    // source (40,96)
    int sr = 40 - I0, sc = 96 - J0;
    bool wave_src = (sc >= 0 && sc < 128) && (sr >= RPL * w) && (sr < RPL * w + RPL);
    int src_rl = sr - RPL * w;
    float srcm = (2 * l == sc) ? 1.f : 0.f;

    // probe: row 160, col 48+48*bj, owned when bi==5
    bool blk_prb = (bi == 5);
    int pcol = 48 + 48 * bj;
    int pr = 160 - I0;
    bool wave_prb = blk_prb && (pr >= RPL * w) && (pr < RPL * w + RPL);
    int prb_rl = pr - RPL * w;
    float prbm = (2 * l == (pcol - J0)) ? 1.f : 0.f;
    float pacc = 0.f;

    __syncthreads();   // hb zeros + xs_l ready

#define STEP(CUR, PRV, PH, SIDX) do {                                          \
    hb[PH][0][w + 1][l] = make_float2(CUR[0][0],  CUR[0][1]);                  \
    hb[PH][1][w + 1][l] = make_float2(CUR[11][0], CUR[11][1]);                 \
    __syncthreads();                                                           \
    float2 uph = hb[PH][1][w][l];       /* bottom row of wave above */         \
    float2 dnh = hb[PH][0][w + 2][l];   /* top row of wave below */            \
    float xsv = xs_l[SIDX];                                                    \
    _Pragma("unroll")                                                          \
    for (int r = 0; r < RPL; r++) {                                            \
        float c0 = CUR[r][0], c1 = CUR[r][1];                                  \
        float lf0 = __shfl_up(c1, 1);   /* col 2l-1 = lane l-1's c1 */         \
        float rt1 = __shfl_down(c0, 1); /* col 2l+2 = lane l+1's c0 */         \
        float up0 = (r == 0)       ? uph.x : CUR[r - 1][0];                    \
        float up1 = (r == 0)       ? uph.y : CUR[r - 1][1];                    \
        float dn0 = (r == RPL - 1) ? dnh.x : CUR[r + 1][0];                    \
        float dn1 = (r == RPL - 1) ? dnh.y : CUR[r + 1][1];                    \
        float yn0 = Pa[r][0] * c0 + Qa[r][0] * PRV[r][0]                       \
                  + Ka[r][0] * ((up0 + dn0) + (lf0 + c1));                     \
        float yn1 = Pa[r][1] * c1 + Qa[r][1] * PRV[r][1]                       \
                  + Ka[r][1] * ((up1 + dn1) + (c0 + rt1));                     \
        if (wave_src && r == src_rl) yn0 += srcm * xsv;                        \
        if (wave_prb && r == prb_rl) { float tq = prbm * yn0; pacc += tq * yn0; } \
        PRV[r][0] = yn0; PRV[r][1] = yn1;                                      \
    }                                                                          \
} while (0)

#pragma unroll 1
    for (int s2 = 0; s2 < TCH / 2; s2++) {
        STEP(yc, yp, 0, 2 * s2);        // new cur -> yp
        STEP(yp, yc, 1, 2 * s2 + 1);    // new cur -> yc
    }
#undef STEP
    // after 32 steps: yc = y(t_end), yp = y(t_end - 1)

    // store out-tile: rows [32bi, 32bi+32), cols [J0+32, J0+96) -> lanes 16..47
#pragma unroll
    for (int r = 0; r < RPL; r++) {
        int gi = row0 + r;
        if (gi >= 32 * bi && gi < 32 * bi + 32 && l >= 16 && l < 48) {
            int idx = gi * NXY + gj;
            *(float2*)(ncurg + idx) = make_float2(yc[r][0], yc[r][1]);
            *(float2*)(nprvg + idx) = make_float2(yp[r][0], yp[r][1]);
        }
    }
    if (wave_prb && prbm == 1.f) ws[I_OFF + b * 3 + bj] += pacc;
}

__global__ void final_k(const float* __restrict__ ws, float* __restrict__ out) {
    int t = threadIdx.x;
    if (t < 12) {
        const float* I = ws + I_OFF;
        int b = t / 3;
        float s = I[3 * b] + I[3 * b + 1] + I[3 * b + 2];
        out[t] = I[t] / s;
    }
}

extern "C" void kernel_launch(void* const* d_in, const int* in_sizes, int n_in,
                              void* d_out, int out_size, void* d_ws, size_t ws_size,
                              hipStream_t stream) {
    const float* x   = (const float*)d_in[0];   // (4,256) fp32
    const float* rho = (const float*)d_in[1];   // (192,192) fp32
    float* ws  = (float*)d_ws;
    float* out = (float*)d_out;

    setup_k<<<256, 256, 0, stream>>>(rho, ws);
    for (int c = 0; c < NCHUNK; c++)
        chunk_k<<<NBATCH * 18, TPB, 0, stream>>>(x, ws, c);
    final_k<<<1, 64, 0, stream>>>(ws, out);
}

// Round 3
// 304.799 us; speedup vs baseline: 1.3574x; 1.0722x over previous
//
#include <hip/hip_runtime.h>
#include <math.h>

#define NXY    192
#define CELLS  (NXY*NXY)
#define NBATCH 4
#define NSTEPS 256
#define TCH    32                 // steps per chunk (= halo width)
#define NCHUNK (NSTEPS/TCH)       // 8
#define TPB    512                // 8 waves
#define RPL    12                 // rows per lane (96 rows / 8 waves)
// in-tile 128 wide x 96 tall; out-tile 64 wide x 32 tall
// grid per batch: 6 row-tiles x 3 col-tiles = 18; total 72 blocks

// workspace layout (float offsets)
#define K3_OFF (16*CELLS)
#define A1_OFF (K3_OFF + CELLS)
#define I_OFF  (A1_OFF + CELLS)

__device__ __forceinline__ float dpp_up1(float v) {
    // lane i <- lane i-1  (v_mov_b32_dpp wave_shr:1, bound_ctrl: lane0 -> 0)
    int r = __builtin_amdgcn_update_dpp(0, __builtin_bit_cast(int, v),
                                        0x138, 0xf, 0xf, true);
    return __builtin_bit_cast(float, r);
}
__device__ __forceinline__ float dpp_dn1(float v) {
    // lane i <- lane i+1  (v_mov_b32_dpp wave_shl:1, bound_ctrl: lane63 -> 0)
    int r = __builtin_amdgcn_update_dpp(0, __builtin_bit_cast(int, v),
                                        0x130, 0xf, 0xf, true);
    return __builtin_bit_cast(float, r);
}

__device__ __forceinline__ float pml_prof(int i) {
    int t;
    if (i <= 20)            t = 20 - i;
    else if (i >= NXY - 21) t = i - (NXY - 21);
    else                    return 0.0f;
    float u  = (float)t * 0.05f;
    float u2 = u * u;
    return 3.0f * u2 * u2;
}

__global__ void setup_k(const float* __restrict__ rho, float* __restrict__ ws) {
    int idx    = blockIdx.x * blockDim.x + threadIdx.x;
    int stride = gridDim.x * blockDim.x;
    for (int k = idx; k < 8 * CELLS; k += stride) ws[k] = 0.0f;
    const float IH2 = (float)(1.0 / (2.01 * 2.01));
    for (int k = idx; k < CELLS; k += stride) {
        int i = k / NXY, j = k % NXY;
        float r0 = rho[k];
        float ru = (i > 0)       ? rho[k - NXY] : 0.0f;
        float rd = (i < NXY - 1) ? rho[k + NXY] : 0.0f;
        float rl = (j > 0)       ? rho[k - 1]   : 0.0f;
        float rr = (j < NXY - 1) ? rho[k + 1]   : 0.0f;
        float lpf = 0.5f * r0 + 0.125f * ((ru + rd) + (rl + rr));
        float p   = 0.5f * (1.0f + tanhf(100.0f * (lpf - 0.5f)));
        float c   = 1.0f - 0.1f * p;
        float c2h = c * c * IH2;
        float bx = pml_prof(i), by = pml_prof(j);
        float bb = sqrtf(bx * bx + by * by);
        float a1 = 1.0f / (1.0f + 0.5f * bb);
        ws[K3_OFF + k] = a1 * c2h;     // K
        ws[A1_OFF + k] = a1;           // A1 (Q derived at load time)
    }
    if (idx < 12) ws[I_OFF + idx] = 0.0f;
}

__global__ __launch_bounds__(TPB, 1)
void chunk_k(const float* __restrict__ x, float* __restrict__ ws, int chunk) {
    int blk = blockIdx.x;
    int b  = blk / 18;
    int rr = blk % 18;
    int bi = rr / 3, bj = rr % 3;
    int I0 = 32 * bi - 32;            // in-tile row origin (may be <0)
    int J0 = 64 * bj - 32;            // in-tile col origin (may be <0)
    int t  = threadIdx.x;
    int w  = t >> 6;                  // wave 0..7, owns rows [12w, 12w+12)
    int l  = t & 63;                  // lane, owns cols 2l, 2l+1 (local)
    int row0 = I0 + RPL * w;          // global row of local r=0
    int gj   = J0 + 2 * l;            // global col of c0 (even)

    // band-boundary halo buffers: [parity][top/bot][slot 0..9][lane]
    // slot w+1 = wave w; slots 0 and 9 stay zero (outside in-tile)
    __shared__ float2 hb[2][2][10][64];
    __shared__ float xs_l[TCH];

    for (int k = t; k < 2 * 2 * 10 * 64; k += TPB)
        ((float2*)hb)[k] = make_float2(0.f, 0.f);
    if (t < TCH) xs_l[t] = x[b * NSTEPS + chunk * TCH + t];

    const float* kg = ws + K3_OFF;
    const float* ag = ws + A1_OFF;
    int pin = chunk & 1, pout = pin ^ 1;
    const float* curg  = ws + ((pin  * 2 + 0) * NBATCH + b) * CELLS;
    const float* prvg  = ws + ((pin  * 2 + 1) * NBATCH + b) * CELLS;
    float*       ncurg = ws + ((pout * 2 + 0) * NBATCH + b) * CELLS;
    float*       nprvg = ws + ((pout * 2 + 1) * NBATCH + b) * CELLS;

    // per-lane state: 4 arrays x 24 = 96 VGPRs
    // update: yn = c + Q*(p - c) + K*(S - 4c)   [P = 1 - Q - 4K eliminated]
    float yc[RPL][2], yp[RPL][2], Qa[RPL][2], Ka[RPL][2];
    bool cok = (gj >= 0 && gj < NXY);
#pragma unroll
    for (int r = 0; r < RPL; r++) {
        int gi = row0 + r;
        bool ok = cok && gi >= 0 && gi < NXY;
        float2 kv = {0.f,0.f}, av = {0.f,0.f}, cv = {0.f,0.f}, pv = {0.f,0.f};
        if (ok) {
            int idx = gi * NXY + gj;
            kv = *(const float2*)(kg + idx);
            av = *(const float2*)(ag + idx);
            cv = *(const float2*)(curg + idx);
            pv = *(const float2*)(prvg + idx);
        }
        yc[r][0] = cv.x; yc[r][1] = cv.y;
        yp[r][0] = pv.x; yp[r][1] = pv.y;
        Ka[r][0] = kv.x; Ka[r][1] = kv.y;
        // out-of-domain (ok=false): K=0, Q=0 -> yn = c = 0 forever. ✓
        Qa[r][0] = ok ? (1.f - 2.f * av.x) : 0.f;
        Qa[r][1] = ok ? (1.f - 2.f * av.y) : 0.f;
    }

    // source (40,96)
    int sr = 40 - I0, sc = 96 - J0;
    bool wave_src = (sc >= 0 && sc < 128) && (sr >= RPL * w) && (sr < RPL * w + RPL);
    int src_rl = sr - RPL * w;
    float srcm = (2 * l == sc) ? 1.f : 0.f;

    // probe: row 160, col 48+48*bj, owned when bi==5
    bool blk_prb = (bi == 5);
    int pcol = 48 + 48 * bj;
    int pr = 160 - I0;
    bool wave_prb = blk_prb && (pr >= RPL * w) && (pr < RPL * w + RPL);
    int prb_rl = pr - RPL * w;
    float prbm = (2 * l == (pcol - J0)) ? 1.f : 0.f;
    float pacc = 0.f;

    __syncthreads();   // hb zeros + xs_l ready

#define STEP(CUR, PRV, PH, SIDX) do {                                          \
    hb[PH][0][w + 1][l] = make_float2(CUR[0][0],  CUR[0][1]);                  \
    hb[PH][1][w + 1][l] = make_float2(CUR[11][0], CUR[11][1]);                 \
    __syncthreads();                                                           \
    float2 uph = hb[PH][1][w][l];       /* bottom row of wave above */         \
    float2 dnh = hb[PH][0][w + 2][l];   /* top row of wave below */            \
    float xsv = xs_l[SIDX];                                                    \
    _Pragma("unroll")                                                          \
    for (int r = 0; r < RPL; r++) {                                            \
        float c0 = CUR[r][0], c1 = CUR[r][1];                                  \
        float lf0 = dpp_up1(c1);        /* col 2l-1 = lane l-1's c1 */         \
        float rt1 = dpp_dn1(c0);        /* col 2l+2 = lane l+1's c0 */         \
        float up0 = (r == 0)       ? uph.x : CUR[r - 1][0];                    \
        float up1 = (r == 0)       ? uph.y : CUR[r - 1][1];                    \
        float dn0 = (r == RPL - 1) ? dnh.x : CUR[r + 1][0];                    \
        float dn1 = (r == RPL - 1) ? dnh.y : CUR[r + 1][1];                    \
        float s0  = (up0 + dn0) + (lf0 + c1);                                  \
        float s1  = (up1 + dn1) + (c0 + rt1);                                  \
        float yn0 = c0 + Qa[r][0] * (PRV[r][0] - c0) + Ka[r][0] * (s0 - 4.f*c0); \
        float yn1 = c1 + Qa[r][1] * (PRV[r][1] - c1) + Ka[r][1] * (s1 - 4.f*c1); \
        if (wave_src && r == src_rl) yn0 += srcm * xsv;                        \
        if (wave_prb && r == prb_rl) { float tq = prbm * yn0; pacc += tq * yn0; } \
        PRV[r][0] = yn0; PRV[r][1] = yn1;                                      \
    }                                                                          \
} while (0)

#pragma unroll 1
    for (int s2 = 0; s2 < TCH / 2; s2++) {
        STEP(yc, yp, 0, 2 * s2);        // new cur -> yp
        STEP(yp, yc, 1, 2 * s2 + 1);    // new cur -> yc
    }
#undef STEP
    // after 32 steps: yc = y(t_end), yp = y(t_end - 1)

    // store out-tile: rows [32bi, 32bi+32), cols [J0+32, J0+96) -> lanes 16..47
#pragma unroll
    for (int r = 0; r < RPL; r++) {
        int gi = row0 + r;
        if (gi >= 32 * bi && gi < 32 * bi + 32 && l >= 16 && l < 48) {
            int idx = gi * NXY + gj;
            *(float2*)(ncurg + idx) = make_float2(yc[r][0], yc[r][1]);
            *(float2*)(nprvg + idx) = make_float2(yp[r][0], yp[r][1]);
        }
    }
    if (wave_prb && prbm == 1.f) ws[I_OFF + b * 3 + bj] += pacc;
}

__global__ void final_k(const float* __restrict__ ws, float* __restrict__ out) {
    int t = threadIdx.x;
    if (t < 12) {
        const float* I = ws + I_OFF;
        int b = t / 3;
        float s = I[3 * b] + I[3 * b + 1] + I[3 * b + 2];
        out[t] = I[t] / s;
    }
}

extern "C" void kernel_launch(void* const* d_in, const int* in_sizes, int n_in,
                              void* d_out, int out_size, void* d_ws, size_t ws_size,
                              hipStream_t stream) {
    const float* x   = (const float*)d_in[0];   // (4,256) fp32
    const float* rho = (const float*)d_in[1];   // (192,192) fp32
    float* ws  = (float*)d_ws;
    float* out = (float*)d_out;

    setup_k<<<256, 256, 0, stream>>>(rho, ws);
    for (int c = 0; c < NCHUNK; c++)
        chunk_k<<<NBATCH * 18, TPB, 0, stream>>>(x, ws, c);
    final_k<<<1, 64, 0, stream>>>(ws, out);
}